// Round 8
// baseline (55.184 us; speedup 1.0000x reference)
//
#include <hip/hip_runtime.h>
#include <hip/hip_cooperative_groups.h>
#include <math.h>

namespace cg = cooperative_groups;

// Problem constants (from reference setup_inputs)
constexpr int NB = 16;      // batch
constexpr int NA = 3;       // anchors
constexpr int NT = 64;      // targets per image
constexpr int NC = 85;      // channels; pred = channel 4
constexpr int G0 = 64, G1 = 32, G2 = 16;
constexpr int N0 = NB * NA * G0 * G0;   // 196608
constexpr int N1 = NB * NA * G1 * G1;   //  49152
constexpr int N2 = NB * NA * G2 * G2;   //  12288
constexpr int BLK = 256;
// one block per (batch, chunk): scale0 12 chunks x 1024, scale1 3 x 1024, scale2 1 x 768
constexpr int NBLK0 = NB * 12;          // 192
constexpr int NBLK1 = NB * 3;           //  48
constexpr int NBLK2 = NB;               //  16
constexpr int NBLK  = NBLK0 + NBLK1 + NBLK2;  // 256

// Per (batch,scale): build gt bitmask in LDS from <=64 targets, then bit-test
// each cell. G compile-time -> divisions become shifts.
template<int G, int NITER>
__device__ __forceinline__ float scale_sum(const float* __restrict__ o,
                                           const float* __restrict__ an,
                                           const float* __restrict__ targets,
                                           int b, int cell0,
                                           unsigned int* __restrict__ mask) {
    constexpr int GG = G * G;
    constexpr int NWORDS = NA * GG / 32;
    const int tid = threadIdx.x;

    for (int k = tid; k < NWORDS; k += BLK) mask[k] = 0u;
    __syncthreads();

    if (tid < NT) {
        const float* tg = targets + (size_t)(b * NT + tid) * 5;
        float tx = tg[1], ty = tg[2];
        float tw = tg[3] * (float)G;
        float th = tg[4] * (float)G;
        float best = -1.0f; int ba = 0;
        #pragma unroll
        for (int a = 0; a < NA; ++a) {
            float aw = an[2 * a], ah = an[2 * a + 1];
            float inter = fminf(aw, tw) * fminf(ah, th);
            float uni = aw * ah + tw * th - inter;
            float iou = inter / uni;
            if (iou > best) { best = iou; ba = a; }  // strict >: first-wins == jnp.argmax
        }
        if (best > 0.5f) {
            int ti = min(max((int)floorf(tx * (float)G), 0), G - 1);
            int tj = min(max((int)floorf(ty * (float)G), 0), G - 1);
            int cell = (ba * G + tj) * G + ti;       // within this batch's scale grid
            atomicOr(&mask[cell >> 5], 1u << (cell & 31));
        }
    }
    __syncthreads();

    float sum = 0.0f;
    #pragma unroll
    for (int k = 0; k < NITER; ++k) {
        int cl = cell0 + k * BLK + tid;              // cell within batch grid
        float pred = o[(size_t)(b * (NA * GG) + cl) * NC + 4];
        float p = fminf(fmaxf(pred, 1e-7f), 1.0f - 1e-7f);
        unsigned int bit = (mask[cl >> 5] >> (cl & 31)) & 1u;
        sum += bit ? (-logf(p)) : (-log1pf(-p));
    }
    return sum;
}

__global__ __launch_bounds__(BLK) void obj_loss_coop(const float* __restrict__ o0,
                                                     const float* __restrict__ o1,
                                                     const float* __restrict__ o2,
                                                     const float* __restrict__ an0,
                                                     const float* __restrict__ an1,
                                                     const float* __restrict__ an2,
                                                     const float* __restrict__ targets,
                                                     double* __restrict__ partials,
                                                     float* __restrict__ out) {
    __shared__ unsigned int mask[NA * G0 * G0 / 32];   // 384 words (max of 3 scales)
    __shared__ double wsum[BLK / 64];
    const int blk = blockIdx.x;
    const int tid = threadIdx.x;

    float s; double w;
    if (blk < NBLK0) {
        int b = blk / 12, c = blk % 12;
        s = scale_sum<G0, 4>(o0, an0, targets, b, c * 1024, mask);
        w = 1.0 / (double)N0;
    } else if (blk < NBLK0 + NBLK1) {
        int r = blk - NBLK0; int b = r / 3, c = r % 3;
        s = scale_sum<G1, 4>(o1, an1, targets, b, c * 1024, mask);
        w = 1.0 / (double)N1;
    } else {
        int b = blk - NBLK0 - NBLK1;
        s = scale_sum<G2, 3>(o2, an2, targets, b, 0, mask);
        w = 1.0 / (double)N2;
    }

    // wave64 shuffle reduce in double, then cross-wave via LDS
    double acc = (double)s;
    #pragma unroll
    for (int off = 32; off > 0; off >>= 1)
        acc += __shfl_down(acc, off);
    const int lane = tid & 63, wv = tid >> 6;
    if (lane == 0) wsum[wv] = acc;
    __syncthreads();
    if (tid == 0) {
        partials[blk] = (wsum[0] + wsum[1] + wsum[2] + wsum[3]) * w;
        __threadfence();   // device-scope visibility before grid barrier
    }

    cg::this_grid().sync();

    if (blk == 0) {
        __shared__ double sm[NBLK];
        sm[tid] = partials[tid];
        __syncthreads();
        #pragma unroll
        for (int off = NBLK / 2; off > 0; off >>= 1) {
            if (tid < off) sm[tid] += sm[tid + off];
            __syncthreads();
        }
        if (tid == 0) out[0] = (float)sm[0];
    }
}

extern "C" void kernel_launch(void* const* d_in, const int* in_sizes, int n_in,
                              void* d_out, int out_size, void* d_ws, size_t ws_size,
                              hipStream_t stream) {
    // setup_inputs() dict order is INTERLEAVED: out0, anchors0, out1, anchors1,
    // out2, anchors2, targets. Guard on in_sizes (deterministic) just in case.
    const float *o0, *o1, *o2, *an0, *an1, *an2, *targets;
    if (in_sizes[1] == 6) {           // interleaved (expected)
        o0  = (const float*)d_in[0];  an0 = (const float*)d_in[1];
        o1  = (const float*)d_in[2];  an1 = (const float*)d_in[3];
        o2  = (const float*)d_in[4];  an2 = (const float*)d_in[5];
    } else {                          // grouped fallback
        o0  = (const float*)d_in[0];  o1  = (const float*)d_in[1];
        o2  = (const float*)d_in[2];  an0 = (const float*)d_in[3];
        an1 = (const float*)d_in[4];  an2 = (const float*)d_in[5];
    }
    targets = (const float*)d_in[6];

    double* partials = (double*)d_ws;   // 256 * 8 B = 2 KB, fully rewritten each call
    float* out = (float*)d_out;

    void* args[] = { (void*)&o0, (void*)&o1, (void*)&o2,
                     (void*)&an0, (void*)&an1, (void*)&an2,
                     (void*)&targets, (void*)&partials, (void*)&out };
    hipLaunchCooperativeKernel((const void*)obj_loss_coop,
                               dim3(NBLK), dim3(BLK), args, 0, stream);
}

// Round 9
// 11.571 us; speedup vs baseline: 4.7690x; 4.7690x over previous
//
#include <hip/hip_runtime.h>
#include <math.h>

// Problem constants (from reference setup_inputs)
constexpr int NB = 16;      // batch
constexpr int NA = 3;       // anchors
constexpr int NT = 64;      // targets per image
constexpr int NC = 85;      // channels; pred = channel 4
constexpr int G0 = 64, G1 = 32, G2 = 16;
constexpr int N0 = NB * NA * G0 * G0;   // 196608
constexpr int N1 = NB * NA * G1 * G1;   //  49152
constexpr int N2 = NB * NA * G2 * G2;   //  12288
constexpr int BLK = 1024;               // 16 waves/block, one cell per thread
// one block per (batch, chunk): scale0 12 chunks x 1024, scale1 3 x 1024, scale2 1 x 768
constexpr int NBLK0 = NB * 12;          // 192
constexpr int NBLK1 = NB * 3;           //  48
constexpr int NBLK2 = NB;               //  16
constexpr int NBLK  = NBLK0 + NBLK1 + NBLK2;  // 256 blocks == 256 CUs

// Per (batch,scale): build gt bitmask in LDS from <=64 targets, then bit-test
// one cell per thread. G compile-time -> divisions become shifts.
template<int G, int NCELLS>
__device__ __forceinline__ float scale_sum(const float* __restrict__ o,
                                           const float* __restrict__ an,
                                           const float* __restrict__ targets,
                                           int b, int cell0,
                                           unsigned int* __restrict__ mask) {
    constexpr int GG = G * G;
    constexpr int NWORDS = NA * GG / 32;
    const int tid = threadIdx.x;

    if (tid < NWORDS) mask[tid] = 0u;     // NWORDS <= 384 < 1024
    __syncthreads();

    if (tid < NT) {
        const float* tg = targets + (size_t)(b * NT + tid) * 5;
        float tx = tg[1], ty = tg[2];
        float tw = tg[3] * (float)G;
        float th = tg[4] * (float)G;
        float best = -1.0f; int ba = 0;
        #pragma unroll
        for (int a = 0; a < NA; ++a) {
            float aw = an[2 * a], ah = an[2 * a + 1];
            float inter = fminf(aw, tw) * fminf(ah, th);
            float uni = aw * ah + tw * th - inter;
            float iou = inter / uni;
            if (iou > best) { best = iou; ba = a; }  // strict >: first-wins == jnp.argmax
        }
        if (best > 0.5f) {
            int ti = min(max((int)floorf(tx * (float)G), 0), G - 1);
            int tj = min(max((int)floorf(ty * (float)G), 0), G - 1);
            int cell = (ba * G + tj) * G + ti;       // within this batch's scale grid
            atomicOr(&mask[cell >> 5], 1u << (cell & 31));
        }
    }
    __syncthreads();

    float term = 0.0f;
    if (tid < NCELLS) {
        int cl = cell0 + tid;                        // cell within batch grid
        float pred = o[(size_t)(b * (NA * GG) + cl) * NC + 4];
        float p = fminf(fmaxf(pred, 1e-7f), 1.0f - 1e-7f);
        unsigned int bit = (mask[cl >> 5] >> (cl & 31)) & 1u;
        term = bit ? (-logf(p)) : (-log1pf(-p));
    }
    return term;
}

__global__ __launch_bounds__(BLK) void obj_loss(const float* __restrict__ o0,
                                                const float* __restrict__ o1,
                                                const float* __restrict__ o2,
                                                const float* __restrict__ an0,
                                                const float* __restrict__ an1,
                                                const float* __restrict__ an2,
                                                const float* __restrict__ targets,
                                                double* __restrict__ partials) {
    __shared__ unsigned int mask[NA * G0 * G0 / 32];   // 384 words (max of 3 scales)
    __shared__ double wsum[BLK / 64];
    const int blk = blockIdx.x;
    const int tid = threadIdx.x;

    float s; double w;
    if (blk < NBLK0) {
        int b = blk / 12, c = blk % 12;
        s = scale_sum<G0, 1024>(o0, an0, targets, b, c * 1024, mask);
        w = 1.0 / (double)N0;
    } else if (blk < NBLK0 + NBLK1) {
        int r = blk - NBLK0; int b = r / 3, c = r % 3;
        s = scale_sum<G1, 1024>(o1, an1, targets, b, c * 1024, mask);
        w = 1.0 / (double)N1;
    } else {
        int b = blk - NBLK0 - NBLK1;
        s = scale_sum<G2, 768>(o2, an2, targets, b, 0, mask);
        w = 1.0 / (double)N2;
    }

    // wave64 shuffle reduce in double, then cross-wave via LDS
    double acc = (double)s;
    #pragma unroll
    for (int off = 32; off > 0; off >>= 1)
        acc += __shfl_down(acc, off);
    const int lane = tid & 63, wv = tid >> 6;
    if (lane == 0) wsum[wv] = acc;
    __syncthreads();
    if (tid == 0) {
        double t = 0.0;
        #pragma unroll
        for (int k = 0; k < BLK / 64; ++k) t += wsum[k];
        partials[blk] = t * w;   // every slot written every call -> poison-safe
    }
}

// single wave: 4 strided loads per lane + shuffle reduce
__global__ __launch_bounds__(64) void finalize(const double* __restrict__ partials,
                                               float* __restrict__ out) {
    const int lane = threadIdx.x;
    double acc = partials[lane] + partials[lane + 64]
               + partials[lane + 128] + partials[lane + 192];
    #pragma unroll
    for (int off = 32; off > 0; off >>= 1)
        acc += __shfl_down(acc, off);
    if (lane == 0) out[0] = (float)acc;
}

extern "C" void kernel_launch(void* const* d_in, const int* in_sizes, int n_in,
                              void* d_out, int out_size, void* d_ws, size_t ws_size,
                              hipStream_t stream) {
    // setup_inputs() dict order is INTERLEAVED: out0, anchors0, out1, anchors1,
    // out2, anchors2, targets. Guard on in_sizes (deterministic) just in case.
    const float *o0, *o1, *o2, *an0, *an1, *an2, *targets;
    if (in_sizes[1] == 6) {           // interleaved (expected)
        o0  = (const float*)d_in[0];  an0 = (const float*)d_in[1];
        o1  = (const float*)d_in[2];  an1 = (const float*)d_in[3];
        o2  = (const float*)d_in[4];  an2 = (const float*)d_in[5];
    } else {                          // grouped fallback
        o0  = (const float*)d_in[0];  o1  = (const float*)d_in[1];
        o2  = (const float*)d_in[2];  an0 = (const float*)d_in[3];
        an1 = (const float*)d_in[4];  an2 = (const float*)d_in[5];
    }
    targets = (const float*)d_in[6];

    double* partials = (double*)d_ws;   // 256 * 8 B = 2 KB, fully rewritten each call

    obj_loss<<<NBLK, BLK, 0, stream>>>(o0, o1, o2, an0, an1, an2, targets, partials);
    finalize<<<1, 64, 0, stream>>>(partials, (float*)d_out);
}